// Round 8
// baseline (46.712 us; speedup 1.0000x reference)
//
#include <hip/hip_runtime.h>
#include <hip/hip_cooperative_groups.h>
#include <math.h>

namespace cg = cooperative_groups;

// SmoothedMedian: B=32, L=1024, C=32, w=32
// out[0..31] = M (per-batch max over t of windowed max distance)
// out[32..63] = R2 (per-batch sum over t of (windowed max distance)^2)
//
// ONE cooperative kernel, grid 32x8 = 256 blocks x 256 thr (1 block/CU).
// Per (batch, 128-center tile): banded Gram via single bf16(RNE) MFMA
// (verified rounds 6-7, absmax 0.0):
//   sq(t,r) = n_t + n_r - 2*G[t,r]   (norms exact fp32; G bf16 dot,
//   err budget: delta(R2) ~0.1 << 2.03 threshold, delta(M) ~1e-4)
// Block partial (max_t maxsq, sum_t maxsq) -> ws slot; grid.sync()
// (device-scope release/acquire across XCDs); the 32 tile-0 blocks
// reduce 8 slots each via shuffle tree (fixed order => deterministic).
// mfma_f32_16x16x32_bf16: A lane l -> row l&15, k=(l>>4)*8+j (K-contig);
// B lane l -> col l&15, same k; D: col=l&15, row=(l>>4)*4+reg  [m89/m91].

#define BB 32
#define LL 1024
#define CC 32
#define WW 32
#define TT 128
#define NROWS (TT + 2*WW)     // 192
#define PADH 40               // bf16 elems/row (80 B): 16B-aligned, bank-spread
#define NTILES (LL / TT)      // 8

typedef __attribute__((ext_vector_type(8))) short bf16x8;
typedef __attribute__((ext_vector_type(4))) float f32x4;

__device__ __forceinline__ unsigned short rne_bf16(float xe) {
    const unsigned ux = __float_as_uint(xe);
    return (unsigned short)((ux + 0x7FFFu + ((ux >> 16) & 1u)) >> 16);
}

__global__ __launch_bounds__(256)
void sm_coop(const float* __restrict__ x, float* __restrict__ ws,
             float* __restrict__ out) {
    const int b    = blockIdx.x;
    const int tile = blockIdx.y;
    const int t0   = tile * TT;
    const int tid  = threadIdx.x;   // 0..255
    const int l    = tid & 63;      // lane
    const int w    = tid >> 6;      // wave 0..3

    cg::grid_group grid = cg::this_grid();

    __shared__ __align__(16) unsigned short hi[NROWS * PADH];  // 15360 B
    __shared__ __align__(16) float nrm_part[NROWS * 8];        //  6144 B
    __shared__ float nrm[NROWS];
    __shared__ float redm[32], redr[32];

    const float* xb = x + (size_t)b * (LL * CC);

    // --- stage 192 rows x 32 ch: fp32 load, RNE->bf16, norm partials ---
    // 192*8 = 1536 float4, 6 per thread, coalesced.
    #pragma unroll
    for (int k = 0; k < 6; ++k) {
        const int f4 = tid + k * 256;      // 0..1535
        const int rr = f4 >> 3;            // local row (8 float4/row)
        const int j  = f4 & 7;
        const int rg = t0 - WW + rr;       // global row
        float4 v = make_float4(0.f, 0.f, 0.f, 0.f);
        if ((unsigned)rg < (unsigned)LL)
            v = *reinterpret_cast<const float4*>(xb + rg * CC + j * 4);
        const float vv[4] = {v.x, v.y, v.z, v.w};
        unsigned short hb[4];
        float s = 0.f;
        #pragma unroll
        for (int e = 0; e < 4; ++e) {
            hb[e] = rne_bf16(vv[e]);
            s = fmaf(vv[e], vv[e], s);
        }
        *reinterpret_cast<ushort4*>(&hi[rr * PADH + j * 4]) = make_ushort4(hb[0], hb[1], hb[2], hb[3]);
        nrm_part[f4] = s;
    }
    __syncthreads();

    if (tid < NROWS) {
        const float4* p = reinterpret_cast<const float4*>(&nrm_part[tid * 8]);
        const float4 a = p[0], c = p[1];
        nrm[tid] = ((a.x + a.y) + (a.z + a.w)) + ((c.x + c.y) + (c.z + c.w));
    }
    __syncthreads();

    const int kc  = (l >> 4) * 8;
    const int col = l & 15;

    // --- wave w owns centers [32w, 32w+32): 2 A-frags x 5 B-tiles ---
    #pragma unroll
    for (int a = 0; a < 2; ++a) {
        const int arB = WW + 32 * w + 16 * a;    // A-frag base LDS row
        const bf16x8 Ah = *reinterpret_cast<const bf16x8*>(&hi[(arB + col) * PADH + kc]);

        float maxsq[4] = {0.f, 0.f, 0.f, 0.f};  // o==0 => 0 is the correct floor
        float ncr[4];
        #pragma unroll
        for (int i = 0; i < 4; ++i)
            ncr[i] = nrm[arB + (l >> 4) * 4 + i];

        #pragma unroll
        for (int ct = 0; ct < 5; ++ct) {
            const int br = arB - 32 + 16 * ct + col;  // window LDS row (lane's col)
            const bf16x8 Bh = *reinterpret_cast<const bf16x8*>(&hi[br * PADH + kc]);
            f32x4 acc = {0.f, 0.f, 0.f, 0.f};
            acc = __builtin_amdgcn_mfma_f32_16x16x32_bf16(Ah, Bh, acc, 0, 0, 0);

            const int rg = t0 - WW + br;              // global window row
            const float nr = nrm[br];
            #pragma unroll
            for (int i = 0; i < 4; ++i) {
                const int ic = 32 * w + 16 * a + (l >> 4) * 4 + i;  // center idx 0..127
                // valid window: br (local) in [ic, ic+64]; global row in [0,L)
                if (br >= ic && br <= ic + 64 && (unsigned)rg < (unsigned)LL) {
                    const float sq = fmaf(-2.0f, acc[i], ncr[i] + nr);
                    maxsq[i] = fmaxf(maxsq[i], sq);
                }
            }
        }

        // 16-lane (col) reduce, then one partial per (wave, frag, group)
        #pragma unroll
        for (int i = 0; i < 4; ++i) {
            float m = maxsq[i];
            #pragma unroll
            for (int s = 1; s < 16; s <<= 1) m = fmaxf(m, __shfl_xor(m, s));
            maxsq[i] = m;
        }
        if (col == 0) {
            float dm = maxsq[0], r2 = maxsq[0];
            #pragma unroll
            for (int i = 1; i < 4; ++i) {
                dm = fmaxf(dm, maxsq[i]);
                r2 += maxsq[i];
            }
            redm[w * 8 + a * 4 + (l >> 4)] = dm;
            redr[w * 8 + a * 4 + (l >> 4)] = r2;
        }
    }
    __syncthreads();

    // 32 partials -> one ws slot (shuffle tree in wave 0, fixed order)
    if (tid < 32) {
        float dm = redm[tid];
        float r2 = redr[tid];
        #pragma unroll
        for (int s = 1; s < 32; s <<= 1) {
            dm = fmaxf(dm, __shfl_xor(dm, s));
            r2 += __shfl_xor(r2, s);
        }
        if (tid == 0)
            reinterpret_cast<float2*>(ws)[b * NTILES + tile] = make_float2(dm, r2);
    }

    // --- grid-wide barrier (device-scope release/acquire) ---
    grid.sync();

    // --- final reduce: 32 tile-0 blocks, 8 slots each, fixed-order tree ---
    if (tile == 0 && tid < NTILES) {
        const float2 v = reinterpret_cast<const float2*>(ws)[b * NTILES + tid];
        float m = v.x;
        float r = v.y;
        #pragma unroll
        for (int s = 1; s < NTILES; s <<= 1) {
            m = fmaxf(m, __shfl_xor(m, s));
            r += __shfl_xor(r, s);
        }
        if (tid == 0) {
            out[b]      = sqrtf(fmaxf(m, 0.f)) * (1.0f / CC);   // M
            out[BB + b] = r * (1.0f / (CC * CC));               // R2 = sum(maxsq)/1024
        }
    }
}

extern "C" void kernel_launch(void* const* d_in, const int* in_sizes, int n_in,
                              void* d_out, int out_size, void* d_ws, size_t ws_size,
                              hipStream_t stream) {
    const float* x  = (const float*)d_in[0];   // (32,1024,32) fp32
    // d_in[1] is w == 32, hardcoded
    float* ws  = (float*)d_ws;                 // 256 float2 slots = 2 KB
    float* out = (float*)d_out;                // 64 floats: M(32) ++ R2(32)

    void* args[] = {(void*)&x, (void*)&ws, (void*)&out};
    hipLaunchCooperativeKernel((const void*)sm_coop, dim3(BB, NTILES), dim3(256),
                               args, 0, stream);
}

// Round 9
// 10.905 us; speedup vs baseline: 4.2834x; 4.2834x over previous
//
#include <hip/hip_runtime.h>
#include <math.h>

// SmoothedMedian: B=32, L=1024, C=32, w=32
// out[0..31] = M (per-batch max over t of windowed max distance)
// out[32..63] = R2 (per-batch sum over t of (windowed max distance)^2)
//
// FINAL (= round-6 measured-best, 10.8 us). Two plain graph nodes:
// Kernel 1 (512 blocks x 256 thr): per (batch, 64-center tile), banded Gram
// via split-bf16 MFMA:
//   x = hi + lo (bit-truncate);  G ~= Ah*Bh + Ah*Bl + Al*Bh  (err ~2^-16 rel)
//   sq(t,r) = n_t + n_r - 2*G[t,r]  (norms exact fp32)
// Block partial = (max_t maxsq, sum_t maxsq) -> ws slot. No atomics/fences
// (r4: fences+memset node = 25.7us; r8: grid.sync = 46.7us; both worse).
// Kernel 2 (1 block x 512 thr): slot t read as one coalesced float2,
// 16-lane shuffle tree per batch (fixed order => deterministic),
// M = sqrt(max)/32, R2 = sum/1024.
// mfma_f32_16x16x32_bf16: A lane l -> row l&15, k=(l>>4)*8+j (K-contig);
// B lane l -> col l&15, same k; D: col=l&15, row=(l>>4)*4+reg  [m89/m91].

#define BB 32
#define LL 1024
#define CC 32
#define WW 32
#define TT 64
#define NROWS (TT + 2*WW)     // 128
#define PADH 40               // bf16 elems/row (80 B): 16B-aligned, bank-spread
#define NTILES (LL / TT)      // 16
#define NBLK (BB * NTILES)    // 512

typedef __attribute__((ext_vector_type(8))) short bf16x8;
typedef __attribute__((ext_vector_type(4))) float f32x4;

__global__ __launch_bounds__(256)
void sm_main(const float* __restrict__ x, float* __restrict__ ws) {
    const int b    = blockIdx.x;
    const int tile = blockIdx.y;
    const int t0   = tile * TT;
    const int tid  = threadIdx.x;   // 0..255
    const int l    = tid & 63;      // lane
    const int w    = tid >> 6;      // wave 0..3

    __shared__ __align__(16) unsigned short hi[NROWS * PADH];
    __shared__ __align__(16) unsigned short lo[NROWS * PADH];
    __shared__ __align__(16) float nrm_part[NROWS * 8];
    __shared__ float nrm[NROWS];
    __shared__ float redm[16], redr[16];

    const float* xb = x + (size_t)b * (LL * CC);

    // --- stage 128 rows x 32 ch: fp32 load, split to bf16 hi/lo, norm partials ---
    #pragma unroll
    for (int k = 0; k < 4; ++k) {
        const int f4 = tid + k * 256;      // 0..1023
        const int rr = f4 >> 3;            // local row (8 float4/row)
        const int j  = f4 & 7;
        const int rg = t0 - WW + rr;       // global row
        float4 v = make_float4(0.f, 0.f, 0.f, 0.f);
        if ((unsigned)rg < (unsigned)LL)
            v = *reinterpret_cast<const float4*>(xb + rg * CC + j * 4);
        float vv[4] = {v.x, v.y, v.z, v.w};
        unsigned short hb[4], lb[4];
        float s = 0.f;
        #pragma unroll
        for (int e = 0; e < 4; ++e) {
            const float xe = vv[e];
            const unsigned ux = __float_as_uint(xe);
            hb[e] = (unsigned short)(ux >> 16);                  // truncate to bf16
            const float hf = __uint_as_float(ux & 0xFFFF0000u);
            const float lf = xe - hf;                            // exact residual
            lb[e] = (unsigned short)(__float_as_uint(lf) >> 16);
            s = fmaf(xe, xe, s);
        }
        *reinterpret_cast<ushort4*>(&hi[rr * PADH + j * 4]) = make_ushort4(hb[0], hb[1], hb[2], hb[3]);
        *reinterpret_cast<ushort4*>(&lo[rr * PADH + j * 4]) = make_ushort4(lb[0], lb[1], lb[2], lb[3]);
        nrm_part[f4] = s;
    }
    __syncthreads();

    if (tid < NROWS) {
        const float4* p = reinterpret_cast<const float4*>(&nrm_part[tid * 8]);
        const float4 a = p[0], c = p[1];
        nrm[tid] = ((a.x + a.y) + (a.z + a.w)) + ((c.x + c.y) + (c.z + c.w));
    }
    __syncthreads();

    // --- A-frag: wave w's 16 centers (local rows 32+16w .. 47+16w) ---
    const int kc = (l >> 4) * 8;
    const int ar = 32 + 16 * w + (l & 15);
    const bf16x8 Ah = *reinterpret_cast<const bf16x8*>(&hi[ar * PADH + kc]);
    const bf16x8 Al = *reinterpret_cast<const bf16x8*>(&lo[ar * PADH + kc]);

    const int col = l & 15;
    float maxsq[4] = {0.f, 0.f, 0.f, 0.f};   // o==0 contributes ~0; floor 0 correct

    // center norms are invariant across the ct loop — hoist
    float ncr[4];
    #pragma unroll
    for (int i = 0; i < 4; ++i)
        ncr[i] = nrm[32 + 16 * w + (l >> 4) * 4 + i];

    // window rows for wave w's centers span local [16w, 16w+79] -> 5 B-tiles
    #pragma unroll
    for (int ct = 0; ct < 5; ++ct) {
        const int br = 16 * w + 16 * ct + col;   // local window row (this lane's col)
        const bf16x8 Bh = *reinterpret_cast<const bf16x8*>(&hi[br * PADH + kc]);
        const bf16x8 Bl = *reinterpret_cast<const bf16x8*>(&lo[br * PADH + kc]);
        f32x4 acc = {0.f, 0.f, 0.f, 0.f};
        acc = __builtin_amdgcn_mfma_f32_16x16x32_bf16(Ah, Bh, acc, 0, 0, 0);
        acc = __builtin_amdgcn_mfma_f32_16x16x32_bf16(Ah, Bl, acc, 0, 0, 0);
        acc = __builtin_amdgcn_mfma_f32_16x16x32_bf16(Al, Bh, acc, 0, 0, 0);

        const int rg = t0 - WW + br;             // global window row
        const float nr = nrm[br];
        #pragma unroll
        for (int i = 0; i < 4; ++i) {
            const int ic = 16 * w + (l >> 4) * 4 + i;   // center index 0..63
            // valid window: br in [ic, ic+64]; global row in [0,L)
            if (br >= ic && br <= ic + 64 && (unsigned)rg < (unsigned)LL) {
                const float sq = fmaf(-2.0f, acc[i], ncr[i] + nr);
                maxsq[i] = fmaxf(maxsq[i], sq);
            }
        }
    }

    // --- 16-lane (col) reduce; per-(wave,group) partials in maxsq domain ---
    #pragma unroll
    for (int i = 0; i < 4; ++i) {
        float m = maxsq[i];
        #pragma unroll
        for (int s = 1; s < 16; s <<= 1) m = fmaxf(m, __shfl_xor(m, s));
        maxsq[i] = m;
    }
    if ((l & 15) == 0) {
        float dm = maxsq[0], r2 = maxsq[0];
        #pragma unroll
        for (int i = 1; i < 4; ++i) {
            dm = fmaxf(dm, maxsq[i]);
            r2 += maxsq[i];
        }
        redm[w * 4 + (l >> 4)] = dm;
        redr[w * 4 + (l >> 4)] = r2;
    }
    __syncthreads();

    // 16 partials -> one slot, shuffle tree in wave 0 (fixed order)
    if (tid < 16) {
        float dm = redm[tid];
        float r2 = redr[tid];
        #pragma unroll
        for (int s = 1; s < 16; s <<= 1) {
            dm = fmaxf(dm, __shfl_xor(dm, s));
            r2 += __shfl_xor(r2, s);
        }
        if (tid == 0)
            reinterpret_cast<float2*>(ws)[b * NTILES + tile] = make_float2(dm, r2);
    }
}

__global__ __launch_bounds__(512)
void sm_reduce(const float* __restrict__ ws, float* __restrict__ out) {
    const int t = threadIdx.x;                 // 0..511, slot index
    const float2 v = reinterpret_cast<const float2*>(ws)[t];   // one coalesced burst
    float m = v.x;    // max of maxsq over this tile
    float r = v.y;    // sum of maxsq over this tile
    #pragma unroll
    for (int s = 1; s < 16; s <<= 1) {         // reduce the 16 tiles of a batch
        m = fmaxf(m, __shfl_xor(m, s));
        r += __shfl_xor(r, s);
    }
    if ((t & 15) == 0) {
        const int b = t >> 4;
        out[b]      = sqrtf(fmaxf(m, 0.f)) * (1.0f / CC);   // M
        out[BB + b] = r * (1.0f / (CC * CC));               // R2 = sum(maxsq)/1024
    }
}

extern "C" void kernel_launch(void* const* d_in, const int* in_sizes, int n_in,
                              void* d_out, int out_size, void* d_ws, size_t ws_size,
                              hipStream_t stream) {
    const float* x  = (const float*)d_in[0];   // (32,1024,32) fp32
    // d_in[1] is w == 32, hardcoded
    float* ws  = (float*)d_ws;                 // 512 float2 slots = 4 KB
    float* out = (float*)d_out;                // 64 floats: M(32) ++ R2(32)

    sm_main<<<dim3(BB, NTILES), 256, 0, stream>>>(x, ws);
    sm_reduce<<<1, 512, 0, stream>>>(ws, out);
}